// Round 4
// baseline (1062.584 us; speedup 1.0000x reference)
//
#include <hip/hip_runtime.h>
#include <math.h>

#define EMBED 2048
#define DFF   8192
#define TOK   4096
#define SEQ   2048
#define HEADS 16
#define HD    128
#define LDQ   6144   // qkv row stride in elements (q|k|v concatenated)

typedef __attribute__((ext_vector_type(8))) short short8;
typedef __attribute__((ext_vector_type(4))) float f32x4;

__device__ __forceinline__ unsigned short f2bf(float f) {
    unsigned int u = __float_as_uint(f);
    return (unsigned short)((u + 0x7FFFu + ((u >> 16) & 1u)) >> 16);  // RNE
}
__device__ __forceinline__ float bf2f(unsigned short s) {
    return __uint_as_float(((unsigned int)s) << 16);
}

// async global->LDS, 16B per lane. LDS dest = wave-uniform base + lane*16.
__device__ __forceinline__ void async16(const void* g, void* l) {
    __builtin_amdgcn_global_load_lds((const __attribute__((address_space(1))) void*)g,
                                     (__attribute__((address_space(3))) void*)l, 16, 0, 0);
}

// ---------------------------------------------------------------------------
// bf16 MFMA GEMM: C[M,N](bf16) = A[M,K](bf16) @ Wt[N,K](bf16)^T + bias (+epi)
// 128x128 tile, BK=32, 256 thr = 4 waves (2x2 of 64x64), 16x16x32 MFMA.
// Single-barrier double-buffered K-loop: loads for tile k+1 are in flight
// across the whole compute phase of tile k (R3's 2-barrier loop exposed the
// full load latency -> MfmaUtil 23%).
// 1D grid, XCD-contiguous tile mapping (M/128 == 32 assumed).
// MODE: 0 plain, 1 +resid f32, 2 +GELU, 3 +resid bf16. Output always bf16.
// ---------------------------------------------------------------------------
template<int MODE>
__global__ __launch_bounds__(256, 2)
void gemm_bf16(const unsigned short* __restrict__ A, const unsigned short* __restrict__ B,
               const float* __restrict__ bias, const void* __restrict__ resid,
               unsigned short* __restrict__ C, int M, int N, int K, int lda)
{
    __shared__ unsigned short As[2][128*32];   // 16 KB
    __shared__ unsigned short Bs[2][128*32];   // 16 KB
    const int t = threadIdx.x;
    const int w = t >> 6, l = t & 63;
    const int quad = l >> 4, m16 = l & 15;

    // XCD-contiguous mapping: xcd = bid&7 gets a contiguous chunk, M-fastest,
    // so each XCD's L2 holds a contiguous N-slab of the weight matrix.
    const int chunk = gridDim.x >> 3;                      // grid % 8 == 0
    const int lin = (blockIdx.x & 7) * chunk + (blockIdx.x >> 3);
    const long bm = (long)(lin & 31) * 128;                // M/128 == 32
    const long bn = (long)(lin >> 5) * 128;

    const int wr = (w >> 1)*64, wc = (w & 1)*64;   // this wave's 64x64 quadrant
    f32x4 acc[4][4] = {};

    const int srow = w*16 + (l >> 2);   // staging row (+u*64)
    const int sslot = l & 3;
    const unsigned short* Ag = A + (size_t)bm*lda;
    const unsigned short* Bg = B + (size_t)bn*K;

    // prologue: stage tile 0 -> buffer 0
#pragma unroll
    for (int u = 0; u < 2; ++u) {
        const int row = u*64 + srow;
        const int c = sslot ^ ((row >> 1) & 3);
        async16(Ag + (size_t)row*lda + c*8, &As[0][u*2048 + w*512]);
        async16(Bg + (size_t)row*K   + c*8, &Bs[0][u*2048 + w*512]);
    }

    const int iters = K >> 5;
    for (int it = 0; it < iters; ++it) {
        __syncthreads();   // drains tile-it glds (in flight since last iter's body)
        if (it + 1 < iters) {
            const int k0 = (it + 1) << 5;
            const int bsel = (it + 1) & 1;
#pragma unroll
            for (int u = 0; u < 2; ++u) {
                const int row = u*64 + srow;
                const int c = sslot ^ ((row >> 1) & 3);
                async16(Ag + (size_t)row*lda + k0 + c*8, &As[bsel][u*2048 + w*512]);
                async16(Bg + (size_t)row*K   + k0 + c*8, &Bs[bsel][u*2048 + w*512]);
            }
        }
        const int cs = it & 1;
        short8 af[4], bf[4];
#pragma unroll
        for (int s = 0; s < 4; ++s) {
            const int ra = wr + s*16 + m16;
            const int sla = quad ^ ((ra >> 1) & 3);
            af[s] = *(const short8*)&As[cs][ra*32 + sla*8];
            const int rb = wc + s*16 + m16;
            const int slb = quad ^ ((rb >> 1) & 3);
            bf[s] = *(const short8*)&Bs[cs][rb*32 + slb*8];
        }
#pragma unroll
        for (int ms = 0; ms < 4; ++ms)
#pragma unroll
            for (int ns = 0; ns < 4; ++ns)
                acc[ms][ns] = __builtin_amdgcn_mfma_f32_16x16x32_bf16(af[ms], bf[ns], acc[ms][ns], 0, 0, 0);
    }

    // epilogue: D row = quad*4+reg, col = lane&15  [verified m89/m91]
#pragma unroll
    for (int ns = 0; ns < 4; ++ns) {
        const long gc = bn + wc + ns*16 + m16;
        const float bcol = bias[gc];
#pragma unroll
        for (int ms = 0; ms < 4; ++ms) {
#pragma unroll
            for (int r = 0; r < 4; ++r) {
                const long gr = bm + wr + ms*16 + quad*4 + r;
                float v = acc[ms][ns][r] + bcol;
                if (MODE == 1) v += ((const float*)resid)[gr*N + gc];
                if (MODE == 3) v += bf2f(((const unsigned short*)resid)[gr*N + gc]);
                if (MODE == 2) v = 0.5f*v*(1.0f + erff(v*0.70710678118654752f));
                C[gr*N + gc] = f2bf(v);
            }
        }
    }
}

// ---------------------------------------------------------------------------
// Flash attention, bf16 MFMA, single-barrier prefetch pipeline. One block =
// (b, h, 64-row Q tile), 256 thr. K staged via glds dbuf; V global reads
// issued BEFORE compute, ds_written into the other Vt buffer AFTER compute.
// Qs aliases Vt[1] (extracted into regs before Vt[1] is first written; the
// prologue barrier after extraction makes that race-free).
// O is written in-place over the Q columns.
// ---------------------------------------------------------------------------
__global__ __launch_bounds__(256, 2)
void attn_flash(unsigned short* __restrict__ qkv)
{
    __shared__ unsigned short Ks[2][64*128];   // 32 KB, slot swizzle (r>>1)&7
    __shared__ unsigned short Vt[2][128*72];   // 36 KB, V^T col j ^ (((d>>5)&3)<<3)
    __shared__ unsigned short Ps[4*16*72];     // 4.5 KB per-wave P scratch
    unsigned short* Qs = &Vt[1][0];            // 16 KB alias (see header comment)

    const int t = threadIdx.x;
    const int w = t >> 6, l = t & 63;
    const int quad = l >> 4, m16 = l & 15;

    const int qt = blockIdx.x & 31;
    const int bh = blockIdx.x >> 5;
    const int b = bh >> 4, h = bh & 15;

    const long rowq = (long)b*SEQ + qt*64;
    const int qc = h*HD;
    const int kc = EMBED + h*HD;
    const int vc = 2*EMBED + h*HD;

    const int rbase = w*4 + (l >> 4);   // glds staging row (+u*16)
    const int slot16 = l & 15;
    const int vslot = t & 15;           // V reg-staging
    const int vrow = t >> 4;

    const int NT = SEQ / 64;

    // ---- prologue: Q glds, K0 glds, V0 reg loads ----
#pragma unroll
    for (int u = 0; u < 4; ++u) {
        const int row = u*16 + rbase;
        const int c = slot16 ^ ((row >> 1) & 7);
        async16(qkv + (rowq + row)*LDQ + qc + c*8, Qs + u*2048 + w*512);
    }
#pragma unroll
    for (int u = 0; u < 4; ++u) {
        const int row = u*16 + rbase;
        const int c = slot16 ^ ((row >> 1) & 7);
        async16(qkv + ((long)b*SEQ + row)*LDQ + kc + c*8, &Ks[0][u*2048 + w*512]);
    }
    short8 va[2], vb[2];
#pragma unroll
    for (int u = 0; u < 2; ++u) {
        const int rp = u*16 + vrow;
        va[u] = *(const short8*)(qkv + ((long)b*SEQ + 2*rp    )*LDQ + vc + vslot*8);
        vb[u] = *(const short8*)(qkv + ((long)b*SEQ + 2*rp + 1)*LDQ + vc + vslot*8);
    }
    __syncthreads();   // Q/K0 in LDS, V0 in regs

    // Q A-frags for the whole loop
    short8 af[4];
#pragma unroll
    for (int ks = 0; ks < 4; ++ks) {
        const int row = w*16 + m16;
        const int sl = (4*ks + quad) ^ ((row >> 1) & 7);
        af[ks] = *(const short8*)&Qs[row*128 + sl*8];
    }
    // V0 -> Vt[0]
#pragma unroll
    for (int u = 0; u < 2; ++u) {
        const int rp = u*16 + vrow;
#pragma unroll
        for (int i = 0; i < 8; ++i) {
            const int d = vslot*8 + i;
            const int col = (2*rp) ^ (((d >> 5) & 3) << 3);
            unsigned int pv = (unsigned int)(unsigned short)va[u][i] |
                              ((unsigned int)(unsigned short)vb[u][i] << 16);
            *(unsigned int*)&Vt[0][d*72 + col] = pv;
        }
    }
    __syncthreads();   // Vt[0] ready; Qs fully consumed -> Vt[1] may be written

    f32x4 O[8] = {};
    float mrun[4] = {-1e30f,-1e30f,-1e30f,-1e30f};
    float lrun[4] = {0.f,0.f,0.f,0.f};
    unsigned short* Pw = Ps + w*16*72;

    for (int kt = 0; kt < NT; ++kt) {
        if (kt > 0) __syncthreads();   // K[kt] glds drained, Vt[kt&1] writes visible
        if (kt + 1 < NT) {
            const long rownext = (long)b*SEQ + (kt + 1)*64;
            const int bsel = (kt + 1) & 1;
#pragma unroll
            for (int u = 0; u < 4; ++u) {
                const int row = u*16 + rbase;
                const int c = slot16 ^ ((row >> 1) & 7);
                async16(qkv + (rownext + row)*LDQ + kc + c*8, &Ks[bsel][u*2048 + w*512]);
            }
#pragma unroll
            for (int u = 0; u < 2; ++u) {
                const int rp = u*16 + vrow;
                va[u] = *(const short8*)(qkv + (rownext + 2*rp    )*LDQ + vc + vslot*8);
                vb[u] = *(const short8*)(qkv + (rownext + 2*rp + 1)*LDQ + vc + vslot*8);
            }
        }
        const int cs = kt & 1;

        // ---- S = Q K^T (16 q-rows per wave x 64 j) ----
        f32x4 S[4];
#pragma unroll
        for (int ns = 0; ns < 4; ++ns) {
            f32x4 a = {0.f,0.f,0.f,0.f};
            const int row = ns*16 + m16;
            const int swr = (row >> 1) & 7;
#pragma unroll
            for (int ks = 0; ks < 4; ++ks) {
                const int sl = (4*ks + quad) ^ swr;
                const short8 bfr = *(const short8*)&Ks[cs][row*128 + sl*8];
                a = __builtin_amdgcn_mfma_f32_16x16x32_bf16(af[ks], bfr, a, 0, 0, 0);
            }
#pragma unroll
            for (int r = 0; r < 4; ++r) a[r] *= 0.08838834764831845f; // 1/sqrt(128)
            S[ns] = a;
        }

        // ---- online softmax (lane holds rows quad*4+r, cols m16) ----
        float al[4], rs[4];
#pragma unroll
        for (int r = 0; r < 4; ++r) {
            float tm = fmaxf(fmaxf(S[0][r], S[1][r]), fmaxf(S[2][r], S[3][r]));
            tm = fmaxf(tm, __shfl_xor(tm, 1));
            tm = fmaxf(tm, __shfl_xor(tm, 2));
            tm = fmaxf(tm, __shfl_xor(tm, 4));
            tm = fmaxf(tm, __shfl_xor(tm, 8));
            const float mn = fmaxf(mrun[r], tm);
            al[r] = __expf(mrun[r] - mn);
            mrun[r] = mn;
            rs[r] = 0.f;
        }
#pragma unroll
        for (int ns = 0; ns < 4; ++ns)
#pragma unroll
            for (int r = 0; r < 4; ++r) {
                const float p = __expf(S[ns][r] - mrun[r]);
                rs[r] += p;
                Pw[(quad*4 + r)*72 + ns*16 + m16] = f2bf(p);
            }
#pragma unroll
        for (int r = 0; r < 4; ++r) {
            rs[r] += __shfl_xor(rs[r], 1);
            rs[r] += __shfl_xor(rs[r], 2);
            rs[r] += __shfl_xor(rs[r], 4);
            rs[r] += __shfl_xor(rs[r], 8);
            lrun[r] = lrun[r]*al[r] + rs[r];
        }
#pragma unroll
        for (int i = 0; i < 8; ++i)
#pragma unroll
            for (int r = 0; r < 4; ++r) O[i][r] *= al[r];

        // ---- O += P V  (P via LDS: C-layout -> A-layout round trip) ----
#pragma unroll
        for (int ks2 = 0; ks2 < 2; ++ks2) {
            const short8 ap = *(const short8*)&Pw[m16*72 + ks2*32 + quad*8];
#pragma unroll
            for (int ds = 0; ds < 8; ++ds) {
                const int d = ds*16 + m16;
                const int jcol = (ks2*32 + quad*8) ^ (((d >> 5) & 3) << 3);
                const short8 bv = *(const short8*)&Vt[cs][d*72 + jcol];
                O[ds] = __builtin_amdgcn_mfma_f32_16x16x32_bf16(ap, bv, O[ds], 0, 0, 0);
            }
        }

        // ---- tail: V(kt+1) regs -> Vt[(kt+1)&1] ----
        if (kt + 1 < NT) {
            const int bsel = (kt + 1) & 1;
#pragma unroll
            for (int u = 0; u < 2; ++u) {
                const int rp = u*16 + vrow;
#pragma unroll
                for (int i = 0; i < 8; ++i) {
                    const int d = vslot*8 + i;
                    const int col = (2*rp) ^ (((d >> 5) & 3) << 3);
                    unsigned int pv = (unsigned int)(unsigned short)va[u][i] |
                                      ((unsigned int)(unsigned short)vb[u][i] << 16);
                    *(unsigned int*)&Vt[bsel][d*72 + col] = pv;
                }
            }
        }
    }

    // ---- normalize + write O over the Q columns ----
    float inv[4];
#pragma unroll
    for (int r = 0; r < 4; ++r) inv[r] = 1.0f / lrun[r];
#pragma unroll
    for (int ds = 0; ds < 8; ++ds)
#pragma unroll
        for (int r = 0; r < 4; ++r) {
            const long row = rowq + w*16 + quad*4 + r;
            qkv[row*LDQ + qc + ds*16 + m16] = f2bf(O[ds][r] * inv[r]);
        }
}

// ---------------------------------------------------------------------------
// LayerNorm over bf16 rows. OUTF32=1 writes fp32 (final output), else bf16.
// ---------------------------------------------------------------------------
template<int OUTF32>
__global__ __launch_bounds__(256)
void ln_bf16(const unsigned short* __restrict__ X, const float* __restrict__ g,
             const float* __restrict__ be, void* __restrict__ Y)
{
    __shared__ float r1[256], r2[256];
    const int t = threadIdx.x;
    const long row = blockIdx.x;
    const unsigned short* x = X + row*EMBED;
    float v[8];
    const short8 xv = *(const short8*)(x + t*8);
    float s = 0.f, s2 = 0.f;
#pragma unroll
    for (int i = 0; i < 8; ++i) {
        v[i] = bf2f((unsigned short)xv[i]);
        s += v[i]; s2 += v[i]*v[i];
    }
    r1[t] = s; r2[t] = s2;
    __syncthreads();
    for (int k = 128; k > 0; k >>= 1) {
        if (t < k) { r1[t] += r1[t+k]; r2[t] += r2[t+k]; }
        __syncthreads();
    }
    const float mu = r1[0] * (1.0f/EMBED);
    const float var = r2[0] * (1.0f/EMBED) - mu*mu;
    const float rstd = rsqrtf(var + 1e-5f);
    if (OUTF32) {
        float* y = (float*)Y + row*EMBED + t*8;
#pragma unroll
        for (int i = 0; i < 8; ++i) y[i] = (v[i]-mu)*rstd*g[t*8+i] + be[t*8+i];
    } else {
        unsigned short* y = (unsigned short*)Y + row*EMBED;
        short8 o;
#pragma unroll
        for (int i = 0; i < 8; ++i) o[i] = (short)f2bf((v[i]-mu)*rstd*g[t*8+i] + be[t*8+i]);
        *(short8*)(y + t*8) = o;
    }
}

// ---------------------------------------------------------------------------
// fp32 W[K][N] -> bf16 Wt[N][K] (transpose + convert), 32x32 LDS tiles
// ---------------------------------------------------------------------------
__global__ __launch_bounds__(256)
void cvt_transpose(const float* __restrict__ W, unsigned short* __restrict__ Wt, int K, int N)
{
    __shared__ unsigned short T[32][33];
    const int t = threadIdx.x;
    const long n0 = (long)blockIdx.x*32, k0 = (long)blockIdx.y*32;
    {
        const int r = t >> 3, c = (t & 7)*4;
        const float4 vv = *(const float4*)&W[(k0 + r)*N + n0 + c];
        T[r][c+0] = f2bf(vv.x); T[r][c+1] = f2bf(vv.y);
        T[r][c+2] = f2bf(vv.z); T[r][c+3] = f2bf(vv.w);
    }
    __syncthreads();
    const int rn = t >> 3, kk = (t & 7)*4;
    unsigned int p0 = (unsigned int)T[kk+0][rn] | ((unsigned int)T[kk+1][rn] << 16);
    unsigned int p1 = (unsigned int)T[kk+2][rn] | ((unsigned int)T[kk+3][rn] << 16);
    unsigned int* dst = (unsigned int*)&Wt[(n0 + rn)*K + k0 + kk];
    dst[0] = p0; dst[1] = p1;
}

__global__ __launch_bounds__(256)
void cvt_f32_bf16(const float* __restrict__ X, unsigned short* __restrict__ Y, long n)
{
    const long i = ((long)blockIdx.x*256 + threadIdx.x)*8;
    if (i >= n) return;
    const float4 a = *(const float4*)&X[i];
    const float4 b = *(const float4*)&X[i+4];
    short8 o;
    o[0]=(short)f2bf(a.x); o[1]=(short)f2bf(a.y); o[2]=(short)f2bf(a.z); o[3]=(short)f2bf(a.w);
    o[4]=(short)f2bf(b.x); o[5]=(short)f2bf(b.y); o[6]=(short)f2bf(b.z); o[7]=(short)f2bf(b.w);
    *(short8*)&Y[i] = o;
}

__global__ __launch_bounds__(256)
void concat_bias(const float* __restrict__ bq, const float* __restrict__ bk,
                 const float* __restrict__ bv, float* __restrict__ out)
{
    const int i = blockIdx.x*256 + threadIdx.x;
    if (i < 2048) out[i] = bq[i];
    else if (i < 4096) out[i] = bk[i-2048];
    else if (i < 6144) out[i] = bv[i-4096];
}

// ---------------------------------------------------------------------------
extern "C" void kernel_launch(void* const* d_in, const int* in_sizes, int n_in,
                              void* d_out, int out_size, void* d_ws, size_t ws_size,
                              hipStream_t stream)
{
    const float* x   = (const float*)d_in[0];
    const float* Wq  = (const float*)d_in[1];
    const float* bq  = (const float*)d_in[2];
    const float* Wk  = (const float*)d_in[3];
    const float* bk  = (const float*)d_in[4];
    const float* Wv  = (const float*)d_in[5];
    const float* bv  = (const float*)d_in[6];
    const float* Wo  = (const float*)d_in[7];
    const float* bo  = (const float*)d_in[8];
    const float* g1  = (const float*)d_in[9];
    const float* b1  = (const float*)d_in[10];
    const float* g2v = (const float*)d_in[11];
    const float* b2v = (const float*)d_in[12];
    const float* W1  = (const float*)d_in[13];
    const float* bf1 = (const float*)d_in[14];
    const float* W2  = (const float*)d_in[15];
    const float* bf2 = (const float*)d_in[16];
    float* out = (float*)d_out;

    // ---- workspace arena (byte offsets; total 184,573,952 B < 192 MiB) ----
    char* ws = (char*)d_ws;
    unsigned short* Wqkvt = (unsigned short*)(ws + 0);          // 25.2 MB [dead after GEMM1]
    unsigned short* Wot   = (unsigned short*)(ws + 25165824);   //  8.4 MB
    unsigned short* W1t   = (unsigned short*)(ws + 33554432);   // 33.6 MB
    unsigned short* W2t   = (unsigned short*)(ws + 67108864);   // 33.6 MB
    float*          bqkv  = (float*)         (ws + 100663296);  // 24 KB
    char* arenaA = ws + 100687872;                              // 67.1 MB arena
    unsigned short* xb   = (unsigned short*)(arenaA);           // 16.8 MB [cvt_x, GEMM1]
    unsigned short* qkv  = (unsigned short*)(arenaA + 16777216);// 50.3 MB [GEMM1, GEMM2]
    unsigned short* res1 = (unsigned short*)(arenaA);           // reuse xb slot [GEMM2, LN1]
    unsigned short* ff   = (unsigned short*)(arenaA);           // full arena [GEMM3, GEMM4]
    unsigned short* hb   = (unsigned short*)(ws + 167796736);   // 16.8 MB [LN1, GEMM4]
    unsigned short* res2 = (unsigned short*)(ws + 0);           // reuse Wqkvt slot [GEMM4, LN2]

    const dim3 blk(256);

    // weights: fp32 -> bf16 transposed
    cvt_transpose<<<dim3(64,64),  blk, 0, stream>>>(Wq, Wqkvt,             2048, 2048);
    cvt_transpose<<<dim3(64,64),  blk, 0, stream>>>(Wk, Wqkvt + 2048*2048, 2048, 2048);
    cvt_transpose<<<dim3(64,64),  blk, 0, stream>>>(Wv, Wqkvt + 2*2048*2048, 2048, 2048);
    cvt_transpose<<<dim3(64,64),  blk, 0, stream>>>(Wo, Wot, 2048, 2048);
    cvt_transpose<<<dim3(256,64), blk, 0, stream>>>(W1, W1t, 2048, 8192);
    cvt_transpose<<<dim3(64,256), blk, 0, stream>>>(W2, W2t, 8192, 2048);
    concat_bias<<<dim3(24), blk, 0, stream>>>(bq, bk, bv, bqkv);
    cvt_f32_bf16<<<dim3(4096), blk, 0, stream>>>(x, xb, (long)TOK*EMBED);

    // fused QKV projection -> qkv[4096][6144]   (1D grids: 32 M-tiles * N/128)
    gemm_bf16<0><<<dim3(32*48), blk, 0, stream>>>(xb, Wqkvt, bqkv, nullptr, qkv, TOK, 6144, 2048, 2048);
    // flash attention (O overwrites q-columns in-place)
    attn_flash<<<dim3(1024), blk, 0, stream>>>(qkv);
    // output projection + residual(x, fp32)
    gemm_bf16<1><<<dim3(32*16), blk, 0, stream>>>(qkv, Wot, bo, x, res1, TOK, 2048, 2048, 6144);
    ln_bf16<0><<<dim3(4096), blk, 0, stream>>>(res1, g1, b1, hb);
    // FFN
    gemm_bf16<2><<<dim3(32*64), blk, 0, stream>>>(hb, W1t, bf1, nullptr, ff, TOK, 8192, 2048, 2048);
    gemm_bf16<3><<<dim3(32*16), blk, 0, stream>>>(ff, W2t, bf2, hb, res2, TOK, 2048, 8192, 8192);
    ln_bf16<1><<<dim3(4096), blk, 0, stream>>>(res2, g2v, b2v, out);
}

// Round 5
// 951.381 us; speedup vs baseline: 1.1169x; 1.1169x over previous
//
#include <hip/hip_runtime.h>
#include <math.h>

#define EMBED 2048
#define DFF   8192
#define TOK   4096
#define SEQ   2048
#define HEADS 16
#define HD    128
#define LDQ   6144   // qkv row stride in elements (q|k|v concatenated)

typedef __attribute__((ext_vector_type(8))) short short8;
typedef __attribute__((ext_vector_type(4))) float f32x4;

__device__ __forceinline__ unsigned short f2bf(float f) {
    unsigned int u = __float_as_uint(f);
    return (unsigned short)((u + 0x7FFFu + ((u >> 16) & 1u)) >> 16);  // RNE
}
__device__ __forceinline__ float bf2f(unsigned short s) {
    return __uint_as_float(((unsigned int)s) << 16);
}

// async global->LDS, 16B per lane. LDS dest = wave-uniform base + lane*16.
__device__ __forceinline__ void async16(const void* g, void* l) {
    __builtin_amdgcn_global_load_lds((const __attribute__((address_space(1))) void*)g,
                                     (__attribute__((address_space(3))) void*)l, 16, 0, 0);
}

// fast GELU (tanh form): v * sigmoid(1.5957691*(v + 0.044715 v^3)); |err|<~1e-3
__device__ __forceinline__ float gelu_fast(float v) {
    const float y = 1.5957691216057308f * (v + 0.044715f * v * v * v);
    return v / (1.0f + __expf(-y));
}

// ---------------------------------------------------------------------------
// bf16 MFMA GEMM: C[M,N](bf16) = A[M,K](bf16) @ Wt[N,K](bf16)^T + bias (+epi)
// 128x128 tile, BK=32, 256 thr = 4 waves (2x2 of 64x64), 16x16x32 MFMA.
// Single-barrier double-buffered K-loop (R4 win: loads for tile k+1 in
// flight across tile k's compute). 2D grid, N-fastest (R3 mapping — the R4
// XCD swizzle raised FETCH 107->168 MB; reverted).
// Epilogue: acc -> LDS (f32, 2 passes) -> 16B coalesced bf16 stores; fixes
// the R4 2x write amplification (scattered 2B stores -> 32B < 64B sector).
// MODE: 0 plain, 1 +resid f32, 2 +GELU, 3 +resid bf16. Output always bf16.
// ---------------------------------------------------------------------------
template<int MODE>
__global__ __launch_bounds__(256, 2)
void gemm_bf16(const unsigned short* __restrict__ A, const unsigned short* __restrict__ B,
               const float* __restrict__ bias, const void* __restrict__ resid,
               unsigned short* __restrict__ C, int M, int N, int K, int lda)
{
    __shared__ __align__(16) float smemf[8448];          // 33.8 KB, multi-use
    unsigned short* As = (unsigned short*)smemf;         // As[2][4096] u16
    unsigned short* Bs = As + 8192;                      // Bs[2][4096] u16
    float* Cs = smemf;                                   // Cs[64][132] f32 (epilogue)

    const int t = threadIdx.x;
    const int w = t >> 6, l = t & 63;
    const int quad = l >> 4, m16 = l & 15;
    const long bm = (long)blockIdx.y * 128, bn = (long)blockIdx.x * 128;
    const int wr = (w >> 1)*64, wc = (w & 1)*64;   // this wave's 64x64 quadrant

    f32x4 acc[4][4] = {};

    const int srow = w*16 + (l >> 2);   // staging row (+u*64)
    const int sslot = l & 3;
    const unsigned short* Ag = A + (size_t)bm*lda;
    const unsigned short* Bg = B + (size_t)bn*K;

    // prologue: stage tile 0 -> buffer 0
#pragma unroll
    for (int u = 0; u < 2; ++u) {
        const int row = u*64 + srow;
        const int c = sslot ^ ((row >> 1) & 3);
        async16(Ag + (size_t)row*lda + c*8, &As[u*2048 + w*512]);
        async16(Bg + (size_t)row*K   + c*8, &Bs[u*2048 + w*512]);
    }

    const int iters = K >> 5;
    for (int it = 0; it < iters; ++it) {
        __syncthreads();   // drains tile-it glds (in flight since last iter)
        if (it + 1 < iters) {
            const int k0 = (it + 1) << 5;
            const int bo = ((it + 1) & 1) * 4096;
#pragma unroll
            for (int u = 0; u < 2; ++u) {
                const int row = u*64 + srow;
                const int c = sslot ^ ((row >> 1) & 3);
                async16(Ag + (size_t)row*lda + k0 + c*8, &As[bo + u*2048 + w*512]);
                async16(Bg + (size_t)row*K   + k0 + c*8, &Bs[bo + u*2048 + w*512]);
            }
        }
        const int co = (it & 1) * 4096;
        short8 af[4], bf[4];
#pragma unroll
        for (int s = 0; s < 4; ++s) {
            const int ra = wr + s*16 + m16;
            const int sla = quad ^ ((ra >> 1) & 3);
            af[s] = *(const short8*)&As[co + ra*32 + sla*8];
            const int rb = wc + s*16 + m16;
            const int slb = quad ^ ((rb >> 1) & 3);
            bf[s] = *(const short8*)&Bs[co + rb*32 + slb*8];
        }
#pragma unroll
        for (int ms = 0; ms < 4; ++ms)
#pragma unroll
            for (int ns = 0; ns < 4; ++ns)
                acc[ms][ns] = __builtin_amdgcn_mfma_f32_16x16x32_bf16(af[ms], bf[ns], acc[ms][ns], 0, 0, 0);
    }

    // ---- epilogue via LDS: 2 passes of 64 rows ----
    const int ecol = (t & 15) * 8;          // this lane's 8 output cols
    float bias8[8];
#pragma unroll
    for (int i = 0; i < 8; ++i) bias8[i] = bias[bn + ecol + i];

#pragma unroll
    for (int pass = 0; pass < 2; ++pass) {
        __syncthreads();   // prior LDS use (K-loop buffers / previous pass) done
        if ((w >> 1) == pass) {   // waves owning rows [pass*64, pass*64+64) stage
#pragma unroll
            for (int ms = 0; ms < 4; ++ms)
#pragma unroll
                for (int ns = 0; ns < 4; ++ns)
#pragma unroll
                    for (int r = 0; r < 4; ++r)
                        Cs[(ms*16 + quad*4 + r)*132 + wc + ns*16 + m16] = acc[ms][ns][r];
        }
        __syncthreads();
#pragma unroll
        for (int j = 0; j < 4; ++j) {
            const int row = j*16 + (t >> 4);
            float v[8];
            *(f32x4*)&v[0] = *(const f32x4*)&Cs[row*132 + ecol];
            *(f32x4*)&v[4] = *(const f32x4*)&Cs[row*132 + ecol + 4];
            const long gr = bm + pass*64 + row;
            const long go = gr*N + bn + ecol;
            float r8[8];
            if (MODE == 1) {
                *(f32x4*)&r8[0] = *(const f32x4*)((const float*)resid + go);
                *(f32x4*)&r8[4] = *(const f32x4*)((const float*)resid + go + 4);
            }
            short8 rb16;
            if (MODE == 3) rb16 = *(const short8*)((const unsigned short*)resid + go);
            short8 o;
#pragma unroll
            for (int i = 0; i < 8; ++i) {
                float y = v[i] + bias8[i];
                if (MODE == 1) y += r8[i];
                if (MODE == 3) y += bf2f((unsigned short)rb16[i]);
                if (MODE == 2) y = gelu_fast(y);
                o[i] = (short)f2bf(y);
            }
            *(short8*)&C[go] = o;
        }
    }
}

// ---------------------------------------------------------------------------
// Flash attention, bf16 MFMA (R3 version — measured good; R4 restructure
// regressed ~170us). One block = (b, h, 64-row Q tile). 256 thr.
// qkv layout: [4096 rows][6144] bf16 = q|k|v, head h at cols h*128 (+0/2048/4096).
// O is written in-place over the Q columns (only this block reads them).
// ---------------------------------------------------------------------------
__global__ __launch_bounds__(256, 2)
void attn_flash(unsigned short* __restrict__ qkv)
{
    __shared__ unsigned short Qs[64*128];   // raw glds layout, 16B-slot swizzle (r>>1)&7
    __shared__ unsigned short Ks[64*128];
    __shared__ unsigned short Vt[128*72];   // V^T [d][j], col j ^ (((d>>5)&3)<<3)
    __shared__ unsigned short Ps[4*16*72];  // per-wave P scratch

    const int t = threadIdx.x;
    const int w = t >> 6, l = t & 63;
    const int quad = l >> 4, m16 = l & 15;

    const int qt = blockIdx.x & 31;
    const int bh = blockIdx.x >> 5;
    const int b = bh >> 4, h = bh & 15;

    const long rowq = (long)b*SEQ + qt*64;
    const int qc = h*HD;
    const int kc = EMBED + h*HD;
    const int vc = 2*EMBED + h*HD;

    // ---- stage Q once ----
    {
        const int rbase = w*4 + (l >> 4);
        const int slot = l & 15;
#pragma unroll
        for (int u = 0; u < 4; ++u) {
            const int row = u*16 + rbase;
            const int c = slot ^ ((row >> 1) & 7);
            async16(qkv + (rowq + row)*LDQ + qc + c*8, Qs + u*2048 + w*512);
        }
    }
    __syncthreads();

    // Q A-frags live in registers for the whole K loop
    short8 af[4];
#pragma unroll
    for (int ks = 0; ks < 4; ++ks) {
        const int row = w*16 + m16;
        const int sl = (4*ks + quad) ^ ((row >> 1) & 7);
        af[ks] = *(const short8*)&Qs[row*128 + sl*8];
    }

    f32x4 O[8] = {};
    float mrun[4] = {-1e30f,-1e30f,-1e30f,-1e30f};
    float lrun[4] = {0.f,0.f,0.f,0.f};
    unsigned short* Pw = Ps + w*16*72;

    for (int kt = 0; kt < SEQ/64; ++kt) {
        const long rowkv = (long)b*SEQ + kt*64;
        __syncthreads();
        // stage K (async, raw)
        {
            const int rbase = w*4 + (l >> 4);
            const int slot = l & 15;
#pragma unroll
            for (int u = 0; u < 4; ++u) {
                const int row = u*16 + rbase;
                const int c = slot ^ ((row >> 1) & 7);
                async16(qkv + (rowkv + row)*LDQ + kc + c*8, &Ks[u*2048 + w*512]);
            }
        }
        // stage V transposed (pack j-pairs -> b32 writes)
        {
            const int slot = t & 15;
#pragma unroll
            for (int u = 0; u < 2; ++u) {
                const int rp = u*16 + (t >> 4);
                const short8 va = *(const short8*)(qkv + (rowkv + 2*rp    )*LDQ + vc + slot*8);
                const short8 vb = *(const short8*)(qkv + (rowkv + 2*rp + 1)*LDQ + vc + slot*8);
#pragma unroll
                for (int i = 0; i < 8; ++i) {
                    const int d = slot*8 + i;
                    const int col = (2*rp) ^ (((d >> 5) & 3) << 3);
                    unsigned int pv = (unsigned int)(unsigned short)va[i] |
                                      ((unsigned int)(unsigned short)vb[i] << 16);
                    *(unsigned int*)&Vt[d*72 + col] = pv;
                }
            }
        }
        __syncthreads();

        // ---- S = Q K^T (16 q-rows per wave x 64 j) ----
        f32x4 S[4];
#pragma unroll
        for (int ns = 0; ns < 4; ++ns) {
            f32x4 a = {0.f,0.f,0.f,0.f};
            const int row = ns*16 + m16;
            const int swr = (row >> 1) & 7;
#pragma unroll
            for (int ks = 0; ks < 4; ++ks) {
                const int sl = (4*ks + quad) ^ swr;
                const short8 bfr = *(const short8*)&Ks[row*128 + sl*8];
                a = __builtin_amdgcn_mfma_f32_16x16x32_bf16(af[ks], bfr, a, 0, 0, 0);
            }
#pragma unroll
            for (int r = 0; r < 4; ++r) a[r] *= 0.08838834764831845f; // 1/sqrt(128)
            S[ns] = a;
        }

        // ---- online softmax (lane holds rows quad*4+r, cols m16) ----
        float al[4], rs[4];
#pragma unroll
        for (int r = 0; r < 4; ++r) {
            float tm = fmaxf(fmaxf(S[0][r], S[1][r]), fmaxf(S[2][r], S[3][r]));
            tm = fmaxf(tm, __shfl_xor(tm, 1));
            tm = fmaxf(tm, __shfl_xor(tm, 2));
            tm = fmaxf(tm, __shfl_xor(tm, 4));
            tm = fmaxf(tm, __shfl_xor(tm, 8));
            const float mn = fmaxf(mrun[r], tm);
            al[r] = __expf(mrun[r] - mn);
            mrun[r] = mn;
            rs[r] = 0.f;
        }
#pragma unroll
        for (int ns = 0; ns < 4; ++ns)
#pragma unroll
            for (int r = 0; r < 4; ++r) {
                const float p = __expf(S[ns][r] - mrun[r]);
                rs[r] += p;
                Pw[(quad*4 + r)*72 + ns*16 + m16] = f2bf(p);
            }
#pragma unroll
        for (int r = 0; r < 4; ++r) {
            rs[r] += __shfl_xor(rs[r], 1);
            rs[r] += __shfl_xor(rs[r], 2);
            rs[r] += __shfl_xor(rs[r], 4);
            rs[r] += __shfl_xor(rs[r], 8);
            lrun[r] = lrun[r]*al[r] + rs[r];
        }
#pragma unroll
        for (int i = 0; i < 8; ++i)
#pragma unroll
            for (int r = 0; r < 4; ++r) O[i][r] *= al[r];

        // ---- O += P V  (P via LDS: C-layout -> A-layout round trip) ----
#pragma unroll
        for (int ks2 = 0; ks2 < 2; ++ks2) {
            const short8 ap = *(const short8*)&Pw[m16*72 + ks2*32 + quad*8];
#pragma unroll
            for (int ds = 0; ds < 8; ++ds) {
                const int d = ds*16 + m16;
                const int jcol = (ks2*32 + quad*8) ^ (((d >> 5) & 3) << 3);
                const short8 bv = *(const short8*)&Vt[d*72 + jcol];
                O[ds] = __builtin_amdgcn_mfma_f32_16x16x32_bf16(ap, bv, O[ds], 0, 0, 0);
            }
        }
    }

    // ---- normalize + write O over the Q columns ----
    float inv[4];
#pragma unroll
    for (int r = 0; r < 4; ++r) inv[r] = 1.0f / lrun[r];
#pragma unroll
    for (int ds = 0; ds < 8; ++ds)
#pragma unroll
        for (int r = 0; r < 4; ++r) {
            const long row = rowq + w*16 + quad*4 + r;
            qkv[row*LDQ + qc + ds*16 + m16] = f2bf(O[ds][r] * inv[r]);
        }
}

// ---------------------------------------------------------------------------
// LayerNorm over bf16 rows. OUTF32=1 writes fp32 (final output), else bf16.
// ---------------------------------------------------------------------------
template<int OUTF32>
__global__ __launch_bounds__(256)
void ln_bf16(const unsigned short* __restrict__ X, const float* __restrict__ g,
             const float* __restrict__ be, void* __restrict__ Y)
{
    __shared__ float r1[256], r2[256];
    const int t = threadIdx.x;
    const long row = blockIdx.x;
    const unsigned short* x = X + row*EMBED;
    float v[8];
    const short8 xv = *(const short8*)(x + t*8);
    float s = 0.f, s2 = 0.f;
#pragma unroll
    for (int i = 0; i < 8; ++i) {
        v[i] = bf2f((unsigned short)xv[i]);
        s += v[i]; s2 += v[i]*v[i];
    }
    r1[t] = s; r2[t] = s2;
    __syncthreads();
    for (int k = 128; k > 0; k >>= 1) {
        if (t < k) { r1[t] += r1[t+k]; r2[t] += r2[t+k]; }
        __syncthreads();
    }
    const float mu = r1[0] * (1.0f/EMBED);
    const float var = r2[0] * (1.0f/EMBED) - mu*mu;
    const float rstd = rsqrtf(var + 1e-5f);
    if (OUTF32) {
        float* y = (float*)Y + row*EMBED + t*8;
#pragma unroll
        for (int i = 0; i < 8; ++i) y[i] = (v[i]-mu)*rstd*g[t*8+i] + be[t*8+i];
    } else {
        unsigned short* y = (unsigned short*)Y + row*EMBED;
        short8 o;
#pragma unroll
        for (int i = 0; i < 8; ++i) o[i] = (short)f2bf((v[i]-mu)*rstd*g[t*8+i] + be[t*8+i]);
        *(short8*)(y + t*8) = o;
    }
}

// ---------------------------------------------------------------------------
// fp32 W[K][N] -> bf16 Wt[N][K] (transpose + convert), 32x32 LDS tiles
// ---------------------------------------------------------------------------
__global__ __launch_bounds__(256)
void cvt_transpose(const float* __restrict__ W, unsigned short* __restrict__ Wt, int K, int N)
{
    __shared__ unsigned short T[32][33];
    const int t = threadIdx.x;
    const long n0 = (long)blockIdx.x*32, k0 = (long)blockIdx.y*32;
    {
        const int r = t >> 3, c = (t & 7)*4;
        const float4 vv = *(const float4*)&W[(k0 + r)*N + n0 + c];
        T[r][c+0] = f2bf(vv.x); T[r][c+1] = f2bf(vv.y);
        T[r][c+2] = f2bf(vv.z); T[r][c+3] = f2bf(vv.w);
    }
    __syncthreads();
    const int rn = t >> 3, kk = (t & 7)*4;
    unsigned int p0 = (unsigned int)T[kk+0][rn] | ((unsigned int)T[kk+1][rn] << 16);
    unsigned int p1 = (unsigned int)T[kk+2][rn] | ((unsigned int)T[kk+3][rn] << 16);
    unsigned int* dst = (unsigned int*)&Wt[(n0 + rn)*K + k0 + kk];
    dst[0] = p0; dst[1] = p1;
}

__global__ __launch_bounds__(256)
void cvt_f32_bf16(const float* __restrict__ X, unsigned short* __restrict__ Y, long n)
{
    const long i = ((long)blockIdx.x*256 + threadIdx.x)*8;
    if (i >= n) return;
    const float4 a = *(const float4*)&X[i];
    const float4 b = *(const float4*)&X[i+4];
    short8 o;
    o[0]=(short)f2bf(a.x); o[1]=(short)f2bf(a.y); o[2]=(short)f2bf(a.z); o[3]=(short)f2bf(a.w);
    o[4]=(short)f2bf(b.x); o[5]=(short)f2bf(b.y); o[6]=(short)f2bf(b.z); o[7]=(short)f2bf(b.w);
    *(short8*)&Y[i] = o;
}

__global__ __launch_bounds__(256)
void concat_bias(const float* __restrict__ bq, const float* __restrict__ bk,
                 const float* __restrict__ bv, float* __restrict__ out)
{
    const int i = blockIdx.x*256 + threadIdx.x;
    if (i < 2048) out[i] = bq[i];
    else if (i < 4096) out[i] = bk[i-2048];
    else if (i < 6144) out[i] = bv[i-4096];
}

// ---------------------------------------------------------------------------
extern "C" void kernel_launch(void* const* d_in, const int* in_sizes, int n_in,
                              void* d_out, int out_size, void* d_ws, size_t ws_size,
                              hipStream_t stream)
{
    const float* x   = (const float*)d_in[0];
    const float* Wq  = (const float*)d_in[1];
    const float* bq  = (const float*)d_in[2];
    const float* Wk  = (const float*)d_in[3];
    const float* bk  = (const float*)d_in[4];
    const float* Wv  = (const float*)d_in[5];
    const float* bv  = (const float*)d_in[6];
    const float* Wo  = (const float*)d_in[7];
    const float* bo  = (const float*)d_in[8];
    const float* g1  = (const float*)d_in[9];
    const float* b1  = (const float*)d_in[10];
    const float* g2v = (const float*)d_in[11];
    const float* b2v = (const float*)d_in[12];
    const float* W1  = (const float*)d_in[13];
    const float* bf1 = (const float*)d_in[14];
    const float* W2  = (const float*)d_in[15];
    const float* bf2 = (const float*)d_in[16];
    float* out = (float*)d_out;

    // ---- workspace arena (byte offsets; total 184,573,952 B < 192 MiB) ----
    char* ws = (char*)d_ws;
    unsigned short* Wqkvt = (unsigned short*)(ws + 0);          // 25.2 MB [dead after GEMM1]
    unsigned short* Wot   = (unsigned short*)(ws + 25165824);   //  8.4 MB
    unsigned short* W1t   = (unsigned short*)(ws + 33554432);   // 33.6 MB
    unsigned short* W2t   = (unsigned short*)(ws + 67108864);   // 33.6 MB
    float*          bqkv  = (float*)         (ws + 100663296);  // 24 KB
    char* arenaA = ws + 100687872;                              // 67.1 MB arena
    unsigned short* xb   = (unsigned short*)(arenaA);           // 16.8 MB [cvt_x, GEMM1]
    unsigned short* qkv  = (unsigned short*)(arenaA + 16777216);// 50.3 MB [GEMM1, GEMM2]
    unsigned short* res1 = (unsigned short*)(arenaA);           // reuse xb slot [GEMM2, LN1]
    unsigned short* ff   = (unsigned short*)(arenaA);           // full arena [GEMM3, GEMM4]
    unsigned short* hb   = (unsigned short*)(ws + 167796736);   // 16.8 MB [LN1, GEMM4]
    unsigned short* res2 = (unsigned short*)(ws + 0);           // reuse Wqkvt slot [GEMM4, LN2]

    const dim3 blk(256);

    // weights: fp32 -> bf16 transposed
    cvt_transpose<<<dim3(64,64),  blk, 0, stream>>>(Wq, Wqkvt,             2048, 2048);
    cvt_transpose<<<dim3(64,64),  blk, 0, stream>>>(Wk, Wqkvt + 2048*2048, 2048, 2048);
    cvt_transpose<<<dim3(64,64),  blk, 0, stream>>>(Wv, Wqkvt + 2*2048*2048, 2048, 2048);
    cvt_transpose<<<dim3(64,64),  blk, 0, stream>>>(Wo, Wot, 2048, 2048);
    cvt_transpose<<<dim3(256,64), blk, 0, stream>>>(W1, W1t, 2048, 8192);
    cvt_transpose<<<dim3(64,256), blk, 0, stream>>>(W2, W2t, 8192, 2048);
    concat_bias<<<dim3(24), blk, 0, stream>>>(bq, bk, bv, bqkv);
    cvt_f32_bf16<<<dim3(4096), blk, 0, stream>>>(x, xb, (long)TOK*EMBED);

    // fused QKV projection -> qkv[4096][6144]
    gemm_bf16<0><<<dim3(48,32), blk, 0, stream>>>(xb, Wqkvt, bqkv, nullptr, qkv, TOK, 6144, 2048, 2048);
    // flash attention (O overwrites q-columns in-place)
    attn_flash<<<dim3(1024), blk, 0, stream>>>(qkv);
    // output projection + residual(x, fp32)
    gemm_bf16<1><<<dim3(16,32), blk, 0, stream>>>(qkv, Wot, bo, x, res1, TOK, 2048, 2048, 6144);
    ln_bf16<0><<<dim3(4096), blk, 0, stream>>>(res1, g1, b1, hb);
    // FFN
    gemm_bf16<2><<<dim3(64,32), blk, 0, stream>>>(hb, W1t, bf1, nullptr, ff, TOK, 8192, 2048, 2048);
    gemm_bf16<3><<<dim3(16,32), blk, 0, stream>>>(ff, W2t, bf2, hb, res2, TOK, 2048, 8192, 8192);
    ln_bf16<1><<<dim3(4096), blk, 0, stream>>>(res2, g2v, b2v, out);
}